// Round 1
// baseline (433.931 us; speedup 1.0000x reference)
//
#include <hip/hip_runtime.h>
#include <hip/hip_bf16.h>
#include <stdint.h>

#define BDIM 4096
#define DDIM 1024
#define KSEL 1024
#define MARGINF 0.5f
#define BIGF 1.0e6f
#define EPSF 1e-6f

typedef __attribute__((ext_vector_type(8))) short short8v;
typedef __attribute__((ext_vector_type(4))) float float4v;

// ---------------- helpers ----------------

__device__ __forceinline__ unsigned short f2bf(float f) {
  // round-to-nearest-even bf16 (values are finite, no NaN path needed)
  uint32_t u = __float_as_uint(f);
  uint32_t r = (u + 0x7FFFu + ((u >> 16) & 1u)) >> 16;
  return (unsigned short)r;
}

__device__ __forceinline__ void gload_lds16(const void* g, void* l) {
  __builtin_amdgcn_global_load_lds(
      (const __attribute__((address_space(1))) void*)g,
      (__attribute__((address_space(3))) void*)l, 16, 0, 0);
}

// ---------------- prep: fp32 -> bf16 + squared norms ----------------
// one wave per row, 4 rows per block
__global__ __launch_bounds__(256) void prep_kernel(
    const float* __restrict__ in, unsigned short* __restrict__ outbf,
    float* __restrict__ norms, float eps) {
  int wave = threadIdx.x >> 6, lane = threadIdx.x & 63;
  int row = blockIdx.x * 4 + wave;
  const float* rp = in + (size_t)row * DDIM;
  unsigned short* op = outbf + (size_t)row * DDIM;
  float acc = 0.f;
#pragma unroll
  for (int it = 0; it < 4; ++it) {
    int k = it * 256 + lane * 4;
    float4 v = *reinterpret_cast<const float4*>(rp + k);
    v.x += eps; v.y += eps; v.z += eps; v.w += eps;
    acc += v.x * v.x + v.y * v.y + v.z * v.z + v.w * v.w;
    ushort4 o;
    o.x = f2bf(v.x); o.y = f2bf(v.y); o.z = f2bf(v.z); o.w = f2bf(v.w);
    *reinterpret_cast<ushort4*>(op + k) = o;
  }
#pragma unroll
  for (int off = 32; off > 0; off >>= 1) acc += __shfl_down(acc, off);
  if (lane == 0) norms[row] = acc;
}

// ---------------- GEMM + distance epilogue ----------------
// 128x128 tile, BK=32, 4 waves (2x2), each wave 64x64 via 4x4 16x16x32 MFMAs
__global__ __launch_bounds__(256) void gemm_dist_kernel(
    const unsigned short* __restrict__ Xb, const unsigned short* __restrict__ Yb,
    const float* __restrict__ xn, const float* __restrict__ yn,
    float* __restrict__ dist) {
  __shared__ unsigned short As[128 * 32];
  __shared__ unsigned short Bs[128 * 32];
  int tid = threadIdx.x;
  int lane = tid & 63, w = tid >> 6;
  int wr = w >> 1, wc = w & 1;
  int brow = blockIdx.y * 128, bcol = blockIdx.x * 128;

  float4v acc[4][4];
#pragma unroll
  for (int m = 0; m < 4; ++m)
#pragma unroll
    for (int n = 0; n < 4; ++n) acc[m][n] = (float4v){0.f, 0.f, 0.f, 0.f};

  int srow = lane >> 2;           // 0..15, row within 16-row chunk
  int scol = (lane & 3) * 8;      // bf16 element offset within 32

  for (int kt = 0; kt < DDIM / 32; ++kt) {
    // stage A and B tiles: each wave covers 32 rows of each via 2 issues
#pragma unroll
    for (int it = 0; it < 2; ++it) {
      int r = w * 32 + it * 16;   // wave-uniform base row in tile
      const unsigned short* gp =
          Xb + (size_t)(brow + r + srow) * DDIM + kt * 32 + scol;
      gload_lds16(gp, As + r * 32);
      const unsigned short* gq =
          Yb + (size_t)(bcol + r + srow) * DDIM + kt * 32 + scol;
      gload_lds16(gq, Bs + r * 32);
    }
    __syncthreads();

    short8v a[4], b[4];
#pragma unroll
    for (int m = 0; m < 4; ++m)
      a[m] = *reinterpret_cast<const short8v*>(
          As + (wr * 64 + m * 16 + (lane & 15)) * 32 + (lane >> 4) * 8);
#pragma unroll
    for (int n = 0; n < 4; ++n)
      b[n] = *reinterpret_cast<const short8v*>(
          Bs + (wc * 64 + n * 16 + (lane & 15)) * 32 + (lane >> 4) * 8);
#pragma unroll
    for (int m = 0; m < 4; ++m)
#pragma unroll
      for (int n = 0; n < 4; ++n)
        acc[m][n] = __builtin_amdgcn_mfma_f32_16x16x32_bf16(a[m], b[n],
                                                            acc[m][n], 0, 0, 0);
    __syncthreads();
  }

  // epilogue: dist = sqrt(max(xn + yn - 2*dot, 0))
#pragma unroll
  for (int m = 0; m < 4; ++m) {
#pragma unroll
    for (int n = 0; n < 4; ++n) {
#pragma unroll
      for (int j = 0; j < 4; ++j) {
        int gr = brow + wr * 64 + m * 16 + (lane >> 4) * 4 + j;
        int gc = bcol + wc * 64 + n * 16 + (lane & 15);
        float sq = xn[gr] + yn[gc] - 2.0f * acc[m][n][j];
        dist[(size_t)gr * BDIM + gc] = sqrtf(fmaxf(sq, 0.f));
      }
    }
  }
}

// ---------------- transpose (32x32 tiles) ----------------
__global__ void transpose_kernel(const float* __restrict__ in,
                                 float* __restrict__ out) {
  __shared__ float tile[32][33];
  int bx = blockIdx.x * 32, by = blockIdx.y * 32;
  int tx = threadIdx.x, ty = threadIdx.y;
#pragma unroll
  for (int i = 0; i < 32; i += 8)
    tile[ty + i][tx] = in[(size_t)(by + ty + i) * BDIM + bx + tx];
  __syncthreads();
#pragma unroll
  for (int i = 0; i < 32; i += 8)
    out[(size_t)(bx + ty + i) * BDIM + by + tx] = tile[tx][ty + i];
}

// ---------------- per-row exact top-K-smallest hinge sum ----------------
// one block per row: radix-select Kth smallest (float bits, positives are
// monotone as uint32), then sum relu(margin+pos-d) over d<T with exact tie fix
__global__ __launch_bounds__(256) void select_kernel(
    const float* __restrict__ dist, float* __restrict__ rowLoss) {
  __shared__ uint32_t sdata[BDIM];
  __shared__ unsigned int hist[256];
  __shared__ uint32_t s_chosen, s_cumBefore;
  __shared__ float wsum[4];
  __shared__ int wcnt[4];

  int tid = threadIdx.x;
  int r = blockIdx.x;
  const float* rowp = dist + (size_t)r * BDIM;
  float pos = rowp[r];  // true diagonal distance (broadcast via cache)

  for (int idx = tid; idx < BDIM; idx += 256) {
    float v = rowp[idx];
    if (idx == r) v = BIGF;
    sdata[idx] = __float_as_uint(v);
  }
  __syncthreads();

  uint32_t prefix = 0, prefMask = 0;
  int kneed = KSEL;
#pragma unroll
  for (int pass = 0; pass < 4; ++pass) {
    int shift = 24 - pass * 8;
    hist[tid] = 0;
    __syncthreads();
    for (int idx = tid; idx < BDIM; idx += 256) {
      uint32_t v = sdata[idx];
      if ((v & prefMask) == prefix) atomicAdd(&hist[(v >> shift) & 0xFFu], 1u);
    }
    __syncthreads();
    if (tid == 0) {
      unsigned int c = 0, bsel = 255, cb = 0;
      for (int b = 0; b < 256; ++b) {
        unsigned int h = hist[b];
        if (c + h >= (unsigned int)kneed) { bsel = b; cb = c; break; }
        c += h;
      }
      s_chosen = bsel;
      s_cumBefore = cb;
    }
    __syncthreads();
    kneed -= (int)s_cumBefore;
    prefix |= (s_chosen << shift);
    prefMask |= (0xFFu << shift);
    __syncthreads();
  }

  float T = __uint_as_float(prefix);
  float local = 0.f;
  int cnt = 0;
  for (int idx = tid; idx < BDIM; idx += 256) {
    uint32_t v = sdata[idx];
    if (v < prefix) {
      float d = __uint_as_float(v);
      local += fmaxf(MARGINF + pos - d, 0.f);
      cnt++;
    }
  }
  int lane = tid & 63, w = tid >> 6;
#pragma unroll
  for (int off = 32; off > 0; off >>= 1) {
    local += __shfl_down(local, off);
    cnt += __shfl_down(cnt, off);
  }
  if (lane == 0) { wsum[w] = local; wcnt[w] = cnt; }
  __syncthreads();
  if (tid == 0) {
    float tot = wsum[0] + wsum[1] + wsum[2] + wsum[3];
    int c = wcnt[0] + wcnt[1] + wcnt[2] + wcnt[3];
    float loss = tot + (float)(KSEL - c) * fmaxf(MARGINF + pos - T, 0.f);
    rowLoss[r] = loss;
  }
}

// ---------------- final reduction ----------------
__global__ void finalize_kernel(const float* __restrict__ rxy,
                                const float* __restrict__ ryx,
                                float* __restrict__ out) {
  const float* src = (blockIdx.x == 0) ? rxy : ryx;
  int tid = threadIdx.x;
  double local = 0.0;
  for (int i = tid; i < BDIM; i += 256) local += (double)src[i];
  int lane = tid & 63, w = tid >> 6;
#pragma unroll
  for (int off = 32; off > 0; off >>= 1) local += __shfl_down(local, off);
  __shared__ double wsd[4];
  if (lane == 0) wsd[w] = local;
  __syncthreads();
  if (tid == 0) {
    double s = wsd[0] + wsd[1] + wsd[2] + wsd[3];
    out[blockIdx.x] = (float)(s / ((double)BDIM * (double)KSEL));
  }
}

// ---------------- launch ----------------
extern "C" void kernel_launch(void* const* d_in, const int* in_sizes, int n_in,
                              void* d_out, int out_size, void* d_ws,
                              size_t ws_size, hipStream_t stream) {
  const float* x = (const float*)d_in[0];
  const float* y = (const float*)d_in[1];
  float* out = (float*)d_out;

  char* ws = (char*)d_ws;
  size_t o = 0;
  auto take = [&](size_t bytes) -> void* {
    void* p = (void*)(ws + o);
    o += (bytes + 255) & ~(size_t)255;
    return p;
  };
  unsigned short* xbf = (unsigned short*)take((size_t)BDIM * DDIM * 2);
  unsigned short* ybf = (unsigned short*)take((size_t)BDIM * DDIM * 2);
  float* xn = (float*)take((size_t)BDIM * 4);
  float* yn = (float*)take((size_t)BDIM * 4);
  float* rxy = (float*)take((size_t)BDIM * 4);
  float* ryx = (float*)take((size_t)BDIM * 4);
  float* dist = (float*)take((size_t)BDIM * BDIM * 4);
  float* distT = (float*)take((size_t)BDIM * BDIM * 4);

  prep_kernel<<<BDIM / 4, 256, 0, stream>>>(x, xbf, xn, EPSF);
  prep_kernel<<<BDIM / 4, 256, 0, stream>>>(y, ybf, yn, 0.f);
  gemm_dist_kernel<<<dim3(BDIM / 128, BDIM / 128), 256, 0, stream>>>(
      xbf, ybf, xn, yn, dist);
  transpose_kernel<<<dim3(BDIM / 32, BDIM / 32), dim3(32, 8), 0, stream>>>(
      dist, distT);
  select_kernel<<<BDIM, 256, 0, stream>>>(dist, rxy);
  select_kernel<<<BDIM, 256, 0, stream>>>(distT, ryx);
  finalize_kernel<<<2, 256, 0, stream>>>(rxy, ryx, out);
}

// Round 2
// 302.760 us; speedup vs baseline: 1.4333x; 1.4333x over previous
//
#include <hip/hip_runtime.h>
#include <hip/hip_bf16.h>
#include <stdint.h>

#define BDIM 4096
#define DDIM 1024
#define KSEL 1024
#define MARGINF 0.5f
#define BIGF 1.0e6f
#define EPSF 1e-6f

typedef __attribute__((ext_vector_type(8))) short short8v;
typedef __attribute__((ext_vector_type(4))) float float4v;

// ---------------- helpers ----------------

__device__ __forceinline__ unsigned short f2bf(float f) {
  uint32_t u = __float_as_uint(f);
  uint32_t r = (u + 0x7FFFu + ((u >> 16) & 1u)) >> 16;
  return (unsigned short)r;
}

__device__ __forceinline__ void gload_lds16(const void* g, void* l) {
  __builtin_amdgcn_global_load_lds(
      (const __attribute__((address_space(1))) void*)g,
      (__attribute__((address_space(3))) void*)l, 16, 0, 0);
}

// ---------------- prep: fp32 -> bf16 + squared norms ----------------
__global__ __launch_bounds__(256) void prep_kernel(
    const float* __restrict__ in, unsigned short* __restrict__ outbf,
    float* __restrict__ norms, float eps) {
  int wave = threadIdx.x >> 6, lane = threadIdx.x & 63;
  int row = blockIdx.x * 4 + wave;
  const float* rp = in + (size_t)row * DDIM;
  unsigned short* op = outbf + (size_t)row * DDIM;
  float acc = 0.f;
#pragma unroll
  for (int it = 0; it < 4; ++it) {
    int k = it * 256 + lane * 4;
    float4 v = *reinterpret_cast<const float4*>(rp + k);
    v.x += eps; v.y += eps; v.z += eps; v.w += eps;
    acc += v.x * v.x + v.y * v.y + v.z * v.z + v.w * v.w;
    ushort4 o;
    o.x = f2bf(v.x); o.y = f2bf(v.y); o.z = f2bf(v.z); o.w = f2bf(v.w);
    *reinterpret_cast<ushort4*>(op + k) = o;
  }
#pragma unroll
  for (int off = 32; off > 0; off >>= 1) acc += __shfl_down(acc, off);
  if (lane == 0) norms[row] = acc;
}

// ---------------- GEMM + distance epilogue (writes dist AND distT) --------
__global__ __launch_bounds__(256) void gemm_dist_kernel(
    const unsigned short* __restrict__ Xb, const unsigned short* __restrict__ Yb,
    const float* __restrict__ xn, const float* __restrict__ yn,
    float* __restrict__ dist, float* __restrict__ distT) {
  __shared__ unsigned short As[128 * 32];
  __shared__ unsigned short Bs[128 * 32];
  int tid = threadIdx.x;
  int lane = tid & 63, w = tid >> 6;
  int wr = w >> 1, wc = w & 1;
  int brow = blockIdx.y * 128, bcol = blockIdx.x * 128;

  float4v acc[4][4];
#pragma unroll
  for (int m = 0; m < 4; ++m)
#pragma unroll
    for (int n = 0; n < 4; ++n) acc[m][n] = (float4v){0.f, 0.f, 0.f, 0.f};

  int srow = lane >> 2;
  int scol = (lane & 3) * 8;

  for (int kt = 0; kt < DDIM / 32; ++kt) {
#pragma unroll
    for (int it = 0; it < 2; ++it) {
      int r = w * 32 + it * 16;
      const unsigned short* gp =
          Xb + (size_t)(brow + r + srow) * DDIM + kt * 32 + scol;
      gload_lds16(gp, As + r * 32);
      const unsigned short* gq =
          Yb + (size_t)(bcol + r + srow) * DDIM + kt * 32 + scol;
      gload_lds16(gq, Bs + r * 32);
    }
    __syncthreads();

    short8v a[4], b[4];
#pragma unroll
    for (int m = 0; m < 4; ++m)
      a[m] = *reinterpret_cast<const short8v*>(
          As + (wr * 64 + m * 16 + (lane & 15)) * 32 + (lane >> 4) * 8);
#pragma unroll
    for (int n = 0; n < 4; ++n)
      b[n] = *reinterpret_cast<const short8v*>(
          Bs + (wc * 64 + n * 16 + (lane & 15)) * 32 + (lane >> 4) * 8);
#pragma unroll
    for (int m = 0; m < 4; ++m)
#pragma unroll
      for (int n = 0; n < 4; ++n)
        acc[m][n] = __builtin_amdgcn_mfma_f32_16x16x32_bf16(a[m], b[n],
                                                            acc[m][n], 0, 0, 0);
    __syncthreads();
  }

  // epilogue: d = sqrt(max(xn + yn - 2*dot, 0)); write dist and distT
#pragma unroll
  for (int m = 0; m < 4; ++m) {
#pragma unroll
    for (int n = 0; n < 4; ++n) {
      int gr0 = brow + wr * 64 + m * 16 + (lane >> 4) * 4;
      int gc = bcol + wc * 64 + n * 16 + (lane & 15);
      float yv = yn[gc];
      float d4[4];
#pragma unroll
      for (int j = 0; j < 4; ++j) {
        float sq = xn[gr0 + j] + yv - 2.0f * acc[m][n][j];
        d4[j] = sqrtf(fmaxf(sq, 0.f));
        dist[(size_t)(gr0 + j) * BDIM + gc] = d4[j];
      }
      *reinterpret_cast<float4*>(&distT[(size_t)gc * BDIM + gr0]) =
          make_float4(d4[0], d4[1], d4[2], d4[3]);
    }
  }
}

// ---------------- per-row exact top-K-smallest hinge sum ----------------
// register-resident keys; exact Kth-smallest via 4-ary binary search on the
// uint bit pattern (positive floats are order-isomorphic to uint32);
// atomic-free block counting (packed uint64), tie-exact correction.
__global__ __launch_bounds__(256) void select_kernel(
    const float* __restrict__ dist, float* __restrict__ rowLoss) {
  __shared__ unsigned long long cred[4];
  __shared__ float fred[4];
  __shared__ int ired[4];
  __shared__ uint32_t mred[8];

  int tid = threadIdx.x;
  int lane = tid & 63, w = tid >> 6;
  int r = blockIdx.x;
  const float* rowp = dist + (size_t)r * BDIM;
  float pos = rowp[r];

  // load 16 keys/thread into registers (coalesced), diagonal -> BIG
  uint32_t key[16];
  uint32_t kmin = 0xFFFFFFFFu, kmax = 0u;
#pragma unroll
  for (int i = 0; i < 16; ++i) {
    int idx = i * 256 + tid;
    float v = rowp[idx];
    uint32_t k = (idx == r) ? __float_as_uint(BIGF) : __float_as_uint(v);
    key[i] = k;
    kmin = min(kmin, k);
    kmax = max(kmax, k);
  }
#pragma unroll
  for (int off = 32; off > 0; off >>= 1) {
    kmin = min(kmin, (uint32_t)__shfl_xor((int)kmin, off));
    kmax = max(kmax, (uint32_t)__shfl_xor((int)kmax, off));
  }
  if (lane == 0) { mred[w] = kmin; mred[4 + w] = kmax; }
  __syncthreads();
  kmin = min(min(mred[0], mred[1]), min(mred[2], mred[3]));
  kmax = max(max(mred[4], mred[5]), max(mred[6], mred[7]));
  __syncthreads();

  // find V_K = Kth smallest key: invariant V_K in [a,b]
  uint32_t a = kmin, b = kmax;
  while (a < b) {
    uint32_t span = b - a;
    uint32_t m1 = a + (span >> 2);
    uint32_t m2 = a + (span >> 1);
    uint32_t m3 = a + span - (span >> 2);
    unsigned long long c = 0;
#pragma unroll
    for (int i = 0; i < 16; ++i) {
      uint32_t k = key[i];
      if (k <= m1) c += 1ull;
      if (k <= m2) c += (1ull << 21);
      if (k <= m3) c += (1ull << 42);
    }
#pragma unroll
    for (int off = 32; off > 0; off >>= 1) c += __shfl_xor(c, off);
    if (lane == 0) cred[w] = c;
    __syncthreads();
    c = cred[0] + cred[1] + cred[2] + cred[3];
    __syncthreads();
    uint32_t c1 = (uint32_t)(c & 0x1FFFFFu);
    uint32_t c2 = (uint32_t)((c >> 21) & 0x1FFFFFu);
    uint32_t c3 = (uint32_t)(c >> 42);
    if (c1 >= KSEL) {
      b = m1;
    } else if (c2 >= KSEL) {
      a = m1 + 1; b = m2;
    } else if (c3 >= KSEL) {
      a = m2 + 1; b = m3;
    } else {
      a = m3 + 1;
    }
  }
  uint32_t T = a;
  float Tf = __uint_as_float(T);

  // hinge sum over keys < T, plus (K - count)·hinge(T) tie correction
  float local = 0.f;
  int cnt = 0;
#pragma unroll
  for (int i = 0; i < 16; ++i) {
    uint32_t k = key[i];
    if (k < T) {
      local += fmaxf(MARGINF + pos - __uint_as_float(k), 0.f);
      cnt++;
    }
  }
#pragma unroll
  for (int off = 32; off > 0; off >>= 1) {
    local += __shfl_xor(local, off);
    cnt += __shfl_xor(cnt, off);
  }
  if (lane == 0) { fred[w] = local; ired[w] = cnt; }
  __syncthreads();
  if (tid == 0) {
    float tot = fred[0] + fred[1] + fred[2] + fred[3];
    int c = ired[0] + ired[1] + ired[2] + ired[3];
    rowLoss[r] = tot + (float)(KSEL - c) * fmaxf(MARGINF + pos - Tf, 0.f);
  }
}

// ---------------- final reduction ----------------
__global__ void finalize_kernel(const float* __restrict__ rxy,
                                const float* __restrict__ ryx,
                                float* __restrict__ out) {
  const float* src = (blockIdx.x == 0) ? rxy : ryx;
  int tid = threadIdx.x;
  double local = 0.0;
  for (int i = tid; i < BDIM; i += 256) local += (double)src[i];
  int lane = tid & 63, w = tid >> 6;
#pragma unroll
  for (int off = 32; off > 0; off >>= 1) local += __shfl_down(local, off);
  __shared__ double wsd[4];
  if (lane == 0) wsd[w] = local;
  __syncthreads();
  if (tid == 0) {
    double s = wsd[0] + wsd[1] + wsd[2] + wsd[3];
    out[blockIdx.x] = (float)(s / ((double)BDIM * (double)KSEL));
  }
}

// ---------------- launch ----------------
extern "C" void kernel_launch(void* const* d_in, const int* in_sizes, int n_in,
                              void* d_out, int out_size, void* d_ws,
                              size_t ws_size, hipStream_t stream) {
  const float* x = (const float*)d_in[0];
  const float* y = (const float*)d_in[1];
  float* out = (float*)d_out;

  char* ws = (char*)d_ws;
  size_t o = 0;
  auto take = [&](size_t bytes) -> void* {
    void* p = (void*)(ws + o);
    o += (bytes + 255) & ~(size_t)255;
    return p;
  };
  unsigned short* xbf = (unsigned short*)take((size_t)BDIM * DDIM * 2);
  unsigned short* ybf = (unsigned short*)take((size_t)BDIM * DDIM * 2);
  float* xn = (float*)take((size_t)BDIM * 4);
  float* yn = (float*)take((size_t)BDIM * 4);
  float* rxy = (float*)take((size_t)BDIM * 4);
  float* ryx = (float*)take((size_t)BDIM * 4);
  float* dist = (float*)take((size_t)BDIM * BDIM * 4);
  float* distT = (float*)take((size_t)BDIM * BDIM * 4);

  prep_kernel<<<BDIM / 4, 256, 0, stream>>>(x, xbf, xn, EPSF);
  prep_kernel<<<BDIM / 4, 256, 0, stream>>>(y, ybf, yn, 0.f);
  gemm_dist_kernel<<<dim3(BDIM / 128, BDIM / 128), 256, 0, stream>>>(
      xbf, ybf, xn, yn, dist, distT);
  select_kernel<<<BDIM, 256, 0, stream>>>(dist, rxy);
  select_kernel<<<BDIM, 256, 0, stream>>>(distT, ryx);
  finalize_kernel<<<2, 256, 0, stream>>>(rxy, ryx, out);
}

// Round 3
// 199.115 us; speedup vs baseline: 2.1793x; 1.5205x over previous
//
#include <hip/hip_runtime.h>
#include <hip/hip_bf16.h>
#include <stdint.h>

#define BDIM 4096
#define DDIM 1024
#define KSEL 1024
#define MARGINF 0.5f
#define BIGF 1.0e6f
#define EPSF 1e-6f

typedef __attribute__((ext_vector_type(8))) short short8v;
typedef __attribute__((ext_vector_type(4))) float float4v;

// ---------------- helpers ----------------

__device__ __forceinline__ unsigned short f2bf(float f) {
  uint32_t u = __float_as_uint(f);
  uint32_t r = (u + 0x7FFFu + ((u >> 16) & 1u)) >> 16;
  return (unsigned short)r;
}

__device__ __forceinline__ void gload_lds16(const void* g, void* l) {
  __builtin_amdgcn_global_load_lds(
      (const __attribute__((address_space(1))) void*)g,
      (__attribute__((address_space(3))) void*)l, 16, 0, 0);
}

// ---------------- prep: fp32 -> bf16 + squared norms ----------------
__global__ __launch_bounds__(256) void prep_kernel(
    const float* __restrict__ in, unsigned short* __restrict__ outbf,
    float* __restrict__ norms, float eps) {
  int wave = threadIdx.x >> 6, lane = threadIdx.x & 63;
  int row = blockIdx.x * 4 + wave;
  const float* rp = in + (size_t)row * DDIM;
  unsigned short* op = outbf + (size_t)row * DDIM;
  float acc = 0.f;
#pragma unroll
  for (int it = 0; it < 4; ++it) {
    int k = it * 256 + lane * 4;
    float4 v = *reinterpret_cast<const float4*>(rp + k);
    v.x += eps; v.y += eps; v.z += eps; v.w += eps;
    acc += v.x * v.x + v.y * v.y + v.z * v.z + v.w * v.w;
    ushort4 o;
    o.x = f2bf(v.x); o.y = f2bf(v.y); o.z = f2bf(v.z); o.w = f2bf(v.w);
    *reinterpret_cast<ushort4*>(op + k) = o;
  }
#pragma unroll
  for (int off = 32; off > 0; off >>= 1) acc += __shfl_down(acc, off);
  if (lane == 0) norms[row] = acc;
}

// ---------------- GEMM + distance epilogue (writes dist AND distT) --------
__global__ __launch_bounds__(256) void gemm_dist_kernel(
    const unsigned short* __restrict__ Xb, const unsigned short* __restrict__ Yb,
    const float* __restrict__ xn, const float* __restrict__ yn,
    float* __restrict__ dist, float* __restrict__ distT) {
  __shared__ unsigned short As[128 * 32];
  __shared__ unsigned short Bs[128 * 32];
  int tid = threadIdx.x;
  int lane = tid & 63, w = tid >> 6;
  int wr = w >> 1, wc = w & 1;
  int brow = blockIdx.y * 128, bcol = blockIdx.x * 128;

  float4v acc[4][4];
#pragma unroll
  for (int m = 0; m < 4; ++m)
#pragma unroll
    for (int n = 0; n < 4; ++n) acc[m][n] = (float4v){0.f, 0.f, 0.f, 0.f};

  int srow = lane >> 2;
  int scol = (lane & 3) * 8;

  for (int kt = 0; kt < DDIM / 32; ++kt) {
#pragma unroll
    for (int it = 0; it < 2; ++it) {
      int r = w * 32 + it * 16;
      const unsigned short* gp =
          Xb + (size_t)(brow + r + srow) * DDIM + kt * 32 + scol;
      gload_lds16(gp, As + r * 32);
      const unsigned short* gq =
          Yb + (size_t)(bcol + r + srow) * DDIM + kt * 32 + scol;
      gload_lds16(gq, Bs + r * 32);
    }
    __syncthreads();

    short8v a[4], b[4];
#pragma unroll
    for (int m = 0; m < 4; ++m)
      a[m] = *reinterpret_cast<const short8v*>(
          As + (wr * 64 + m * 16 + (lane & 15)) * 32 + (lane >> 4) * 8);
#pragma unroll
    for (int n = 0; n < 4; ++n)
      b[n] = *reinterpret_cast<const short8v*>(
          Bs + (wc * 64 + n * 16 + (lane & 15)) * 32 + (lane >> 4) * 8);
#pragma unroll
    for (int m = 0; m < 4; ++m)
#pragma unroll
      for (int n = 0; n < 4; ++n)
        acc[m][n] = __builtin_amdgcn_mfma_f32_16x16x32_bf16(a[m], b[n],
                                                            acc[m][n], 0, 0, 0);
    __syncthreads();
  }

#pragma unroll
  for (int m = 0; m < 4; ++m) {
#pragma unroll
    for (int n = 0; n < 4; ++n) {
      int gr0 = brow + wr * 64 + m * 16 + (lane >> 4) * 4;
      int gc = bcol + wc * 64 + n * 16 + (lane & 15);
      float yv = yn[gc];
      float d4[4];
#pragma unroll
      for (int j = 0; j < 4; ++j) {
        float sq = xn[gr0 + j] + yv - 2.0f * acc[m][n][j];
        d4[j] = sqrtf(fmaxf(sq, 0.f));
        dist[(size_t)(gr0 + j) * BDIM + gc] = d4[j];
      }
      *reinterpret_cast<float4*>(&distT[(size_t)gc * BDIM + gr0]) =
          make_float4(d4[0], d4[1], d4[2], d4[3]);
    }
  }
}

// ---------------- per-row exact top-K-smallest hinge sum ----------------
// one WAVE per row, 64 keys/lane in VGPRs, barrier-free.
// Exact Kth-smallest semantics via: any T with count(<T) <= K <= count(<=T)
// gives loss = sum_{k<T} h(k) + (K - count_less)*h(T) exactly, so a
// binary-search midpoint capturing exactly K elements terminates early.
__global__ __launch_bounds__(256, 4) void select_kernel(
    const float* __restrict__ dist, const float* __restrict__ distT,
    float* __restrict__ rxy, float* __restrict__ ryx) {
  int lane = threadIdx.x & 63, w = threadIdx.x >> 6;
  int r = blockIdx.x * 4 + w;           // 0..8191
  int rr = (r < BDIM) ? r : r - BDIM;   // row within matrix
  const float* rowp = ((r < BDIM) ? dist : distT) + (size_t)rr * BDIM;
  float pos = rowp[rr];

  // load 64 keys/lane (float4-coalesced); raw min/max bracket the Kth value
  uint32_t key[64];
  uint32_t kmin = 0xFFFFFFFFu, kmax = 0u;
#pragma unroll
  for (int i = 0; i < 16; ++i) {
    int idx0 = i * 256 + lane * 4;
    uint4 v = *reinterpret_cast<const uint4*>(rowp + idx0);
    kmin = min(kmin, min(min(v.x, v.y), min(v.z, v.w)));
    kmax = max(kmax, max(max(v.x, v.y), max(v.z, v.w)));
    key[i * 4 + 0] = (idx0 + 0 == rr) ? __float_as_uint(BIGF) : v.x;
    key[i * 4 + 1] = (idx0 + 1 == rr) ? __float_as_uint(BIGF) : v.y;
    key[i * 4 + 2] = (idx0 + 2 == rr) ? __float_as_uint(BIGF) : v.z;
    key[i * 4 + 3] = (idx0 + 3 == rr) ? __float_as_uint(BIGF) : v.w;
  }
#pragma unroll
  for (int off = 32; off > 0; off >>= 1) {
    kmin = min(kmin, (uint32_t)__shfl_xor((int)kmin, off));
    kmax = max(kmax, (uint32_t)__shfl_xor((int)kmax, off));
  }

  // binary search for a valid threshold (ballot+popcount counting)
  uint32_t a = kmin, b = kmax;
  uint32_t T;
  bool found = false;
  while (a < b) {
    uint32_t m = a + ((b - a) >> 1);
    int c = 0;
#pragma unroll
    for (int i = 0; i < 64; ++i) c += __popcll(__ballot(key[i] <= m));
    if (c == KSEL) { T = m; found = true; break; }
    if (c > KSEL) b = m; else a = m + 1;
  }
  if (!found) T = a;

  // hinge sum over keys < T, plus (K - cnt_less)*h(T) tie/threshold term
  float Tf = __uint_as_float(T);
  float pm = MARGINF + pos;
  float local = 0.f;
  int cnt_less = 0;
#pragma unroll
  for (int i = 0; i < 64; ++i) {
    uint32_t k = key[i];
    cnt_less += __popcll(__ballot(k < T));
    float h = fmaxf(pm - __uint_as_float(k), 0.f);
    local += (k < T) ? h : 0.f;
  }
#pragma unroll
  for (int off = 32; off > 0; off >>= 1) local += __shfl_xor(local, off);
  if (lane == 0) {
    float loss = local + (float)(KSEL - cnt_less) * fmaxf(pm - Tf, 0.f);
    if (r < BDIM) rxy[rr] = loss; else ryx[rr] = loss;
  }
}

// ---------------- final reduction ----------------
__global__ void finalize_kernel(const float* __restrict__ rxy,
                                const float* __restrict__ ryx,
                                float* __restrict__ out) {
  const float* src = (blockIdx.x == 0) ? rxy : ryx;
  int tid = threadIdx.x;
  double local = 0.0;
  for (int i = tid; i < BDIM; i += 256) local += (double)src[i];
  int lane = tid & 63, w = tid >> 6;
#pragma unroll
  for (int off = 32; off > 0; off >>= 1) local += __shfl_down(local, off);
  __shared__ double wsd[4];
  if (lane == 0) wsd[w] = local;
  __syncthreads();
  if (tid == 0) {
    double s = wsd[0] + wsd[1] + wsd[2] + wsd[3];
    out[blockIdx.x] = (float)(s / ((double)BDIM * (double)KSEL));
  }
}

// ---------------- launch ----------------
extern "C" void kernel_launch(void* const* d_in, const int* in_sizes, int n_in,
                              void* d_out, int out_size, void* d_ws,
                              size_t ws_size, hipStream_t stream) {
  const float* x = (const float*)d_in[0];
  const float* y = (const float*)d_in[1];
  float* out = (float*)d_out;

  char* ws = (char*)d_ws;
  size_t o = 0;
  auto take = [&](size_t bytes) -> void* {
    void* p = (void*)(ws + o);
    o += (bytes + 255) & ~(size_t)255;
    return p;
  };
  unsigned short* xbf = (unsigned short*)take((size_t)BDIM * DDIM * 2);
  unsigned short* ybf = (unsigned short*)take((size_t)BDIM * DDIM * 2);
  float* xn = (float*)take((size_t)BDIM * 4);
  float* yn = (float*)take((size_t)BDIM * 4);
  float* rxy = (float*)take((size_t)BDIM * 4);
  float* ryx = (float*)take((size_t)BDIM * 4);
  float* dist = (float*)take((size_t)BDIM * BDIM * 4);
  float* distT = (float*)take((size_t)BDIM * BDIM * 4);

  prep_kernel<<<BDIM / 4, 256, 0, stream>>>(x, xbf, xn, EPSF);
  prep_kernel<<<BDIM / 4, 256, 0, stream>>>(y, ybf, yn, 0.f);
  gemm_dist_kernel<<<dim3(BDIM / 128, BDIM / 128), 256, 0, stream>>>(
      xbf, ybf, xn, yn, dist, distT);
  select_kernel<<<2 * BDIM / 4, 256, 0, stream>>>(dist, distT, rxy, ryx);
  finalize_kernel<<<2, 256, 0, stream>>>(rxy, ryx, out);
}

// Round 4
// 165.695 us; speedup vs baseline: 2.6189x; 1.2017x over previous
//
#include <hip/hip_runtime.h>
#include <hip/hip_bf16.h>
#include <stdint.h>

#define BDIM 4096
#define DDIM 1024
#define KSEL 1024
#define MARGINF 0.5f
#define EPSF 1e-6f

typedef __attribute__((ext_vector_type(8))) short short8v;
typedef __attribute__((ext_vector_type(4))) float float4v;

// ---------------- helpers ----------------

__device__ __forceinline__ unsigned short f2bf(float f) {
  uint32_t u = __float_as_uint(f);
  uint32_t r = (u + 0x7FFFu + ((u >> 16) & 1u)) >> 16;
  return (unsigned short)r;
}

__device__ __forceinline__ void gload_lds16(const void* g, void* l) {
  __builtin_amdgcn_global_load_lds(
      (const __attribute__((address_space(1))) void*)g,
      (__attribute__((address_space(3))) void*)l, 16, 0, 0);
}

// ---------------- prep: fp32 -> bf16 + squared norms (x and y merged) -----
__global__ __launch_bounds__(256) void prep_kernel(
    const float* __restrict__ x, const float* __restrict__ y,
    unsigned short* __restrict__ xbf, unsigned short* __restrict__ ybf,
    float* __restrict__ xn, float* __restrict__ yn) {
  int wave = threadIdx.x >> 6, lane = threadIdx.x & 63;
  int row = blockIdx.x * 4 + wave;  // 0..8191
  bool isx = row < BDIM;
  int rr = isx ? row : row - BDIM;
  const float* rp = (isx ? x : y) + (size_t)rr * DDIM;
  unsigned short* op = (isx ? xbf : ybf) + (size_t)rr * DDIM;
  float eps = isx ? EPSF : 0.f;
  float acc = 0.f;
#pragma unroll
  for (int it = 0; it < 4; ++it) {
    int k = it * 256 + lane * 4;
    float4 v = *reinterpret_cast<const float4*>(rp + k);
    v.x += eps; v.y += eps; v.z += eps; v.w += eps;
    acc += v.x * v.x + v.y * v.y + v.z * v.z + v.w * v.w;
    ushort4 o;
    o.x = f2bf(v.x); o.y = f2bf(v.y); o.z = f2bf(v.z); o.w = f2bf(v.w);
    *reinterpret_cast<ushort4*>(op + k) = o;
  }
#pragma unroll
  for (int off = 32; off > 0; off >>= 1) acc += __shfl_down(acc, off);
  if (lane == 0) (isx ? xn : yn)[rr] = acc;
}

// ---------------- GEMM + distance epilogue (bf16 dist, distT; fp32 diag) --
__global__ __launch_bounds__(256) void gemm_dist_kernel(
    const unsigned short* __restrict__ Xb, const unsigned short* __restrict__ Yb,
    const float* __restrict__ xn, const float* __restrict__ yn,
    unsigned short* __restrict__ dist, unsigned short* __restrict__ distT,
    float* __restrict__ posv) {
  __shared__ unsigned short As[128 * 32];
  __shared__ unsigned short Bs[128 * 32];
  int tid = threadIdx.x;
  int lane = tid & 63, w = tid >> 6;
  int wr = w >> 1, wc = w & 1;
  // XCD-aware swizzle over the 32x32 grid (1024 wgs, 1024%8==0 -> bijective)
  int wg = blockIdx.y * 32 + blockIdx.x;
  int swz = (wg & 7) * 128 + (wg >> 3);
  int brow = (swz >> 5) * 128, bcol = (swz & 31) * 128;

  float4v acc[4][4];
#pragma unroll
  for (int m = 0; m < 4; ++m)
#pragma unroll
    for (int n = 0; n < 4; ++n) acc[m][n] = (float4v){0.f, 0.f, 0.f, 0.f};

  int srow = lane >> 2;
  int scol = (lane & 3) * 8;

  for (int kt = 0; kt < DDIM / 32; ++kt) {
#pragma unroll
    for (int it = 0; it < 2; ++it) {
      int r = w * 32 + it * 16;
      const unsigned short* gp =
          Xb + (size_t)(brow + r + srow) * DDIM + kt * 32 + scol;
      gload_lds16(gp, As + r * 32);
      const unsigned short* gq =
          Yb + (size_t)(bcol + r + srow) * DDIM + kt * 32 + scol;
      gload_lds16(gq, Bs + r * 32);
    }
    __syncthreads();

    short8v a[4], b[4];
#pragma unroll
    for (int m = 0; m < 4; ++m)
      a[m] = *reinterpret_cast<const short8v*>(
          As + (wr * 64 + m * 16 + (lane & 15)) * 32 + (lane >> 4) * 8);
#pragma unroll
    for (int n = 0; n < 4; ++n)
      b[n] = *reinterpret_cast<const short8v*>(
          Bs + (wc * 64 + n * 16 + (lane & 15)) * 32 + (lane >> 4) * 8);
#pragma unroll
    for (int m = 0; m < 4; ++m)
#pragma unroll
      for (int n = 0; n < 4; ++n)
        acc[m][n] = __builtin_amdgcn_mfma_f32_16x16x32_bf16(a[m], b[n],
                                                            acc[m][n], 0, 0, 0);
    __syncthreads();
  }

  // epilogue: d = sqrt(max(xn + yn - 2*dot, 0)); bf16 stores, fp32 diagonal
#pragma unroll
  for (int m = 0; m < 4; ++m) {
#pragma unroll
    for (int n = 0; n < 4; ++n) {
      int gr0 = brow + wr * 64 + m * 16 + (lane >> 4) * 4;
      int gc = bcol + wc * 64 + n * 16 + (lane & 15);
      float yv = yn[gc];
      ushort4 st;
      unsigned short* sp = reinterpret_cast<unsigned short*>(&st);
#pragma unroll
      for (int j = 0; j < 4; ++j) {
        float sq = xn[gr0 + j] + yv - 2.0f * acc[m][n][j];
        float d = sqrtf(fmaxf(sq, 0.f));
        sp[j] = f2bf(d);
        dist[(size_t)(gr0 + j) * BDIM + gc] = sp[j];
        if (gr0 + j == gc) posv[gc] = d;  // exact fp32 diagonal
      }
      *reinterpret_cast<ushort4*>(&distT[(size_t)gc * BDIM + gr0]) = st;
    }
  }
}

// ---------------- per-row exact top-K-smallest hinge sum (bf16 keys) ------
// one WAVE per row, 64 u16 keys/lane, barrier-free. Any T with
// count(<T) <= K <= count(<=T) gives exact loss via tie-correction.
__global__ __launch_bounds__(256, 4) void select_kernel(
    const unsigned short* __restrict__ dist,
    const unsigned short* __restrict__ distT,
    const float* __restrict__ posv,
    float* __restrict__ rxy, float* __restrict__ ryx) {
  int lane = threadIdx.x & 63, w = threadIdx.x >> 6;
  int r = blockIdx.x * 4 + w;           // 0..8191
  int rr = (r < BDIM) ? r : r - BDIM;
  const unsigned short* rowp =
      ((r < BDIM) ? dist : distT) + (size_t)rr * BDIM;
  float pos = posv[rr];

  // load 64 keys/lane (16B-coalesced); raw min/max bracket the Kth value
  uint32_t key[64];
  uint32_t kmin = 0xFFFFu, kmax = 0u;
#pragma unroll
  for (int i = 0; i < 8; ++i) {
    int idx0 = i * 512 + lane * 8;
    uint4 v = *reinterpret_cast<const uint4*>(rowp + idx0);
    uint32_t pk[4] = {v.x, v.y, v.z, v.w};
#pragma unroll
    for (int p = 0; p < 4; ++p) {
      uint32_t lo = pk[p] & 0xFFFFu, hi = pk[p] >> 16;
      kmin = min(kmin, min(lo, hi));
      kmax = max(kmax, max(lo, hi));
      int idx = idx0 + p * 2;
      key[i * 8 + p * 2 + 0] = (idx + 0 == rr) ? 0xFFFFu : lo;
      key[i * 8 + p * 2 + 1] = (idx + 1 == rr) ? 0xFFFFu : hi;
    }
  }
#pragma unroll
  for (int off = 32; off > 0; off >>= 1) {
    kmin = min(kmin, (uint32_t)__shfl_xor((int)kmin, off));
    kmax = max(kmax, (uint32_t)__shfl_xor((int)kmax, off));
  }

  // binary search over the (tiny) u16 code span
  uint32_t a = kmin, b = kmax;
  uint32_t T;
  bool found = false;
  while (a < b) {
    uint32_t m = (a + b) >> 1;
    int c = 0;
#pragma unroll
    for (int i = 0; i < 64; ++i) c += __popcll(__ballot(key[i] <= m));
    if (c == KSEL) { T = m; found = true; break; }
    if (c > KSEL) b = m; else a = m + 1;
  }
  if (!found) T = a;

  // hinge sum over keys < T, plus (K - cnt_less)*h(T) tie/threshold term
  float Tf = __uint_as_float(T << 16);
  float pm = MARGINF + pos;
  float local = 0.f;
  int cnt_less = 0;
#pragma unroll
  for (int i = 0; i < 64; ++i) {
    uint32_t k = key[i];
    cnt_less += __popcll(__ballot(k < T));
    float d = __uint_as_float(k << 16);
    local += (k < T) ? fmaxf(pm - d, 0.f) : 0.f;
  }
#pragma unroll
  for (int off = 32; off > 0; off >>= 1) local += __shfl_xor(local, off);
  if (lane == 0) {
    float loss = local + (float)(KSEL - cnt_less) * fmaxf(pm - Tf, 0.f);
    if (r < BDIM) rxy[rr] = loss; else ryx[rr] = loss;
  }
}

// ---------------- final reduction ----------------
__global__ void finalize_kernel(const float* __restrict__ rxy,
                                const float* __restrict__ ryx,
                                float* __restrict__ out) {
  const float* src = (blockIdx.x == 0) ? rxy : ryx;
  int tid = threadIdx.x;
  double local = 0.0;
  for (int i = tid; i < BDIM; i += 256) local += (double)src[i];
  int lane = tid & 63, w = tid >> 6;
#pragma unroll
  for (int off = 32; off > 0; off >>= 1) local += __shfl_down(local, off);
  __shared__ double wsd[4];
  if (lane == 0) wsd[w] = local;
  __syncthreads();
  if (tid == 0) {
    double s = wsd[0] + wsd[1] + wsd[2] + wsd[3];
    out[blockIdx.x] = (float)(s / ((double)BDIM * (double)KSEL));
  }
}

// ---------------- launch ----------------
extern "C" void kernel_launch(void* const* d_in, const int* in_sizes, int n_in,
                              void* d_out, int out_size, void* d_ws,
                              size_t ws_size, hipStream_t stream) {
  const float* x = (const float*)d_in[0];
  const float* y = (const float*)d_in[1];
  float* out = (float*)d_out;

  char* ws = (char*)d_ws;
  size_t o = 0;
  auto take = [&](size_t bytes) -> void* {
    void* p = (void*)(ws + o);
    o += (bytes + 255) & ~(size_t)255;
    return p;
  };
  unsigned short* xbf = (unsigned short*)take((size_t)BDIM * DDIM * 2);
  unsigned short* ybf = (unsigned short*)take((size_t)BDIM * DDIM * 2);
  float* xn = (float*)take((size_t)BDIM * 4);
  float* yn = (float*)take((size_t)BDIM * 4);
  float* rxy = (float*)take((size_t)BDIM * 4);
  float* ryx = (float*)take((size_t)BDIM * 4);
  float* posv = (float*)take((size_t)BDIM * 4);
  unsigned short* dist = (unsigned short*)take((size_t)BDIM * BDIM * 2);
  unsigned short* distT = (unsigned short*)take((size_t)BDIM * BDIM * 2);

  prep_kernel<<<2 * BDIM / 4, 256, 0, stream>>>(x, y, xbf, ybf, xn, yn);
  gemm_dist_kernel<<<dim3(32, 32), 256, 0, stream>>>(xbf, ybf, xn, yn, dist,
                                                     distT, posv);
  select_kernel<<<2 * BDIM / 4, 256, 0, stream>>>(dist, distT, posv, rxy, ryx);
  finalize_kernel<<<2, 256, 0, stream>>>(rxy, ryx, out);
}